// Round 4
// baseline (114.264 us; speedup 1.0000x reference)
//
#include <hip/hip_runtime.h>
#include <math.h>

// StructureLoss — R11: single fused kernel; global L2 as the transpose buffer.
// R10 post-mortem: both passes beat the 40us fill individually, but 3 launches
// + a cross-kernel 67MB S round-trip ate the gain (headline noise band ±6us,
// ~65us of harness fill/overhead). Key fix: the horizontal box needs S of the
// SAME rows the vertical pass produced -> the S dependency is row-local, so
// both passes fuse into ONE kernel with ONE __syncthreads. Each block: 32-row
// segment, thread-per-col register ring (zero LDS, zero barriers) -> writes S
// (65KB/block, L2-resident on this CU) -> barrier -> reads its own S rows
// back (L2 hits) for prefix/scan/elementwise. t center rows re-read from
// global are L2/L3-hot (read by phase 1 moments earlier). 512 blocks
// (2/CU, 16 waves), 2 barriers total, 2 dispatches total. Summation order
// identical to R10 (vert ring / q16 prefix / width-32 scan / red order /
// final g-order) -> bitwise-stable, absmax 0.

#define IMG_H 512
#define IMG_W 512
#define NB    32
#define HW    (IMG_H * IMG_W)
#define SEGR  32              // rows per block segment

__device__ __forceinline__ float wave_reduce(float v) {
#pragma unroll
  for (int off = 32; off > 0; off >>= 1) v += __shfl_down(v, off, 64);
  return v;
}

// 512 blocks: xcd(8) x k(64); img = 4 per XCD, seg = 16 per img.
// Same-XCD segs share t halo rows in that XCD's L2.
__global__ __launch_bounds__(512, 4) void sloss_main(const float* __restrict__ x,
                                                     const float* __restrict__ t,
                                                     float* __restrict__ S,
                                                     float* __restrict__ part) {
  __shared__ float red4[2][8][4];

  const int tid = threadIdx.x;
  const int bid = blockIdx.x;
  const int xcd = bid & 7;
  const int k   = bid >> 3;                // 0..63
  const int img = (xcd << 2) | (k >> 4);   // 4 images per XCD
  const int seg = k & 15;                  // 16 segments per image
  const int r0  = seg * SEGR;              // multiple of 32 -> ring idx static

  // ---- Phase 1: vertical 31-box sums, thread-per-col, register ring ----
  {
    const float* tc = t + (size_t)img * HW + tid;
    float*       Sc = S + (size_t)img * HW + tid;

    float win[32];
#pragma unroll
    for (int i = 0; i < 32; ++i) win[i] = 0.f;

    float sum = 0.f;
    {
      float w[30];
#pragma unroll
      for (int j = 0; j < 30; ++j) {
        int r = r0 - 15 + j;
        w[j] = ((unsigned)r < IMG_H) ? tc[(size_t)r * IMG_W] : 0.f;
      }
#pragma unroll
      for (int j = 0; j < 30; ++j) {
        sum += w[j];
        win[(j + 17) & 31] = w[j];         // slot for row r0-15+j
      }
    }

#pragma unroll
    for (int bch = 0; bch < 2; ++bch) {
      float h[16];
#pragma unroll
      for (int j = 0; j < 16; ++j) {
        int r = r0 + bch * 16 + j + 15;
        h[j] = (r < IMG_H) ? tc[(size_t)r * IMG_W] : 0.f;
      }
#pragma unroll
      for (int j = 0; j < 16; ++j) {
        const int rr = bch * 16 + j;       // 0..31 (compile-time)
        sum += h[j];
        Sc[(size_t)(r0 + rr) * IMG_W] = sum;
        sum -= win[(rr + 17) & 31];        // row r0+rr-15
        win[(rr + 15) & 31] = h[j];        // row r0+rr+15
      }
    }
  }

  __syncthreads();   // drains vmcnt -> this block's S writes visible via L1/L2

  // ---- Phase 2: horizontal box + fused elementwise, 2 x 16-row groups ----
  const int row = tid >> 5;                // 0..15
  const int sub = tid & 31;                // 16-col chunk 0..31
  const float inv_area = 1.0f / 961.0f;

#pragma unroll
  for (int g = 0; g < 2; ++g) {
    const size_t base =
        (size_t)img * HW + (size_t)(r0 + g * 16 + row) * IMG_W + 16 * sub;

    float4 sg[4], xg[4], tg[4];
#pragma unroll
    for (int e = 0; e < 4; ++e) sg[e] = *(const float4*)(S + base + 4 * e);
#pragma unroll
    for (int e = 0; e < 4; ++e) xg[e] = *(const float4*)(x + base + 4 * e);
#pragma unroll
    for (int e = 0; e < 4; ++e) tg[e] = *(const float4*)(t + base + 4 * e);

    float q16[16];
    {
      float run = 0.f;
#pragma unroll
      for (int e = 0; e < 4; ++e) {
        q16[4 * e + 0] = run + sg[e].x;
        q16[4 * e + 1] = q16[4 * e + 0] + sg[e].y;
        q16[4 * e + 2] = q16[4 * e + 1] + sg[e].z;
        q16[4 * e + 3] = q16[4 * e + 2] + sg[e].w;
        run = q16[4 * e + 3];
      }
    }
    {
      float tot = q16[15], ss = tot;
#pragma unroll
      for (int d = 1; d < 32; d <<= 1) {
        float uu = __shfl_up(ss, d, 64);
        if (sub >= d) ss += uu;
      }
      float pb = ss - tot;
#pragma unroll
      for (int j = 0; j < 16; ++j) q16[j] += pb;   // q16[j] = P[16*sub + j]
    }

    float aW = 0.f, aWB = 0.f, aI = 0.f, aU = 0.f;
#pragma unroll
    for (int e = 0; e < 4; ++e) {
      float xa[4] = {xg[e].x, xg[e].y, xg[e].z, xg[e].w};
      float ta[4] = {tg[e].x, tg[e].y, tg[e].z, tg[e].w};
#pragma unroll
      for (int l = 0; l < 4; ++l) {
        const int j = 4 * e + l;
        float hi;
        if (j == 0) {
          hi = q16[15];
        } else {
          float gd = __shfl_down(q16[j - 1], 1, 64);
          hi = (sub == 31) ? q16[15] : gd;           // P[min(c+15,511)]
        }
        float gu = __shfl_up(q16[j], 1, 64);
        float lo = (sub == 0) ? 0.f : gu;            // P[c-16] or 0
        float box = hi - lo;
        float tv = ta[l], xv = xa[l];
        float w   = fmaf(5.0f, fabsf(box * inv_area - tv), 1.0f);
        float ez  = __expf(-fabsf(xv));
        float iv  = 1.0f / (1.0f + ez);
        float p   = (xv >= 0.f) ? iv : ez * iv;      // sigmoid(x)
        float bce = fmaxf(xv, 0.f) - xv * tv + __logf(1.0f + ez);
        aW  += w;
        aWB = fmaf(w, bce, aWB);
        aI  = fmaf(p * tv, w, aI);
        aU  = fmaf(p + tv, w, aU);
      }
    }

    aW  = wave_reduce(aW);
    aWB = wave_reduce(aWB);
    aI  = wave_reduce(aI);
    aU  = wave_reduce(aU);
    const int wv = tid >> 6, ln = tid & 63;
    if (ln == 0) {
      red4[g][wv][0] = aW; red4[g][wv][1] = aWB;
      red4[g][wv][2] = aI; red4[g][wv][3] = aU;
    }
    // no barrier between g: disjoint red4 slots
  }

  __syncthreads();
  if (tid < 8) {
    const int g = tid >> 2, q = tid & 3;
    float v = 0.f;
#pragma unroll
    for (int w8 = 0; w8 < 8; ++w8) v += red4[g][w8][q];
    part[((img * 32) + (seg * 2 + g)) * 4 + q] = v;   // grp16 = seg*2+g
  }
}

// ---- finalize: reduce 1024 block-partials -> scalar loss (same as R10) ----
__global__ void sloss_final(const float* __restrict__ part,
                            float* __restrict__ out) {
  __shared__ float s[128];
  int tid = threadIdx.x;          // 128 threads
  int img = tid >> 2, q = tid & 3;
  float v = 0.f;
#pragma unroll 4
  for (int g = 0; g < 32; ++g) v += part[((img << 5) + g) * 4 + q];
  s[tid] = v;
  __syncthreads();
  float loss = 0.f;
  if (tid < NB) {
    float aW  = s[tid * 4 + 0];
    float aWB = s[tid * 4 + 1];
    float aI  = s[tid * 4 + 2];
    float aU  = s[tid * 4 + 3];
    loss = aWB / aW + 1.0f - (aI + 1.0f) / (aU - aI + 1.0f);
  }
  loss = wave_reduce(loss);
  if (tid == 0) out[0] = loss * (1.0f / (float)NB);
}

extern "C" void kernel_launch(void* const* d_in, const int* in_sizes, int n_in,
                              void* d_out, int out_size, void* d_ws, size_t ws_size,
                              hipStream_t stream) {
  const float* x = (const float*)d_in[0];
  const float* t = (const float*)d_in[1];
  float* S    = (float*)d_ws;                      // 32*512*512 f32 = 33.5 MB
  float* part = (float*)d_ws + (size_t)NB * HW;    // 1024 x 4 f32

  sloss_main<<<512, 512, 0, stream>>>(x, t, S, part);
  sloss_final<<<1, 128, 0, stream>>>(part, (float*)d_out);
}

// Round 5
// 104.849 us; speedup vs baseline: 1.0898x; 1.0898x over previous
//
#include <hip/hip_runtime.h>
#include <math.h>

// StructureLoss — R12: R8 (best known, 102.3) + de-drained barriers ONLY.
// Cross-round normalization: headline = fill(41us) + main-chain + ~22us gaps;
// rocprof kernel times are inflated vs the timing run (R9 main "71us" was
// ~43 by headline math). Deltas vs R8: R9(+5.7)=sched_barrier(0) pinning
// (m141 trap), R10(+10.3)/R11(+12.0)=S-through-global round-trip. So: the
// rolling-LDS-window structure of R8 is right; the remaining defect is the
// 10 __syncthreads each draining vmcnt(0), force-stalling the 64KB/iter
// prefetch instead of letting it fly under stage-2 compute. R12 swaps the
// in-loop + prologue barriers for {s_waitcnt lgkmcnt(0); s_barrier} with a
// "memory" clobber and NO sched_barrier — all cross-thread handoffs are
// LDS (lgkm-counted); global prefetches are same-thread with compiler
// counted-vmcnt waits. Everything else is byte-identical to R8.

#define IMG_H 512
#define IMG_W 512
#define NB    32
#define BANDS 8               // 64-row bands per image
#define NBLK  (NB * BANDS)    // 256 blocks, 1 per CU
#define NTH   512
#define TSR   580             // t-window row stride (floats): 512 + 64 skew + pad
#define SLOT  (16 * TSR)      // one 16-row slot
#define VST   584             // vls row stride (floats)

// LDS-only barrier: waits DS ops (cross-thread handoff) but does NOT drain
// vmcnt -> global prefetches stream across barriers. No sched_barrier(0):
// let the compiler schedule freely (R9's pinning was the regression).
#define LDS_BAR()                                                              \
  do {                                                                         \
    asm volatile("s_waitcnt lgkmcnt(0)" ::: "memory");                         \
    __builtin_amdgcn_s_barrier();                                              \
  } while (0)

// skew: col c stored at c + 4*(c>>5); 32-col chunk s occupies [36s, 36s+31]
__device__ __forceinline__ float wave_reduce(float v) {
#pragma unroll
  for (int off = 32; off > 0; off >>= 1) v += __shfl_down(v, off, 64);
  return v;
}

// load one 16-row t block (rows 16b..16b+15) into 4 float4 regs, zero-fill OOR
__device__ __forceinline__ void load_blk(const float* __restrict__ tb, int b,
                                         int tid, float4* g) {
#pragma unroll
  for (int q = 0; q < 4; ++q) {
    int idx = q * NTH + tid;
    int gr  = b * 16 + (idx >> 7);
    int c4  = idx & 127;
    g[q] = ((unsigned)gr < IMG_H)
               ? *(const float4*)(tb + (size_t)gr * IMG_W + 4 * c4)
               : make_float4(0.f, 0.f, 0.f, 0.f);
  }
}

// write a staged 16-row block into LDS slot with the vidx skew
__device__ __forceinline__ void store_blk(float* dst, int slot, int tid,
                                          const float4* g) {
#pragma unroll
  for (int q = 0; q < 4; ++q) {
    int idx = q * NTH + tid;
    int r16 = idx >> 7;
    int cc  = (idx & 127) * 4;
    *(float4*)&dst[slot * SLOT + r16 * TSR + cc + 4 * (cc >> 5)] = g[q];
  }
}

// x tile for 16 rows starting at R0: thread (row=tid>>5, sub=tid&31), 16 cols
__device__ __forceinline__ void load_x(const float* __restrict__ xb, int R0,
                                       int tid, float4* g) {
  const int row = tid >> 5, sub = tid & 31;
  const float* xr = xb + (size_t)(R0 + row) * IMG_W + 16 * sub;
#pragma unroll
  for (int e = 0; e < 4; ++e) g[e] = *(const float4*)(xr + 4 * e);
}

#define ITER(K, XG, TPF, XGN, TPFN)                                            \
  {                                                                            \
    const int bbk   = bb0 + (K);                                               \
    const int R0    = bbk * 16;                                                \
    const int sPrev = (bbk + 2) % 3;                                           \
    const int sCur  = bbk % 3;                                                 \
    const int sNext = (bbk + 1) % 3;                                           \
    _Pragma("unroll")                                                          \
    for (int i = 0; i < 16; ++i) {                                             \
      const int sHd = (i >= 1) ? sNext : sCur;                                 \
      const int sTl = (i < 15) ? sPrev : sCur;                                 \
      float hd = ts[sHd * SLOT + ((i + 15) & 15) * TSR + li];                  \
      float tl = ts[sTl * SLOT + ((i + 1) & 15) * TSR + li];                   \
      sx += hd;                                                                \
      vls[i * VST + li] = sx;                                                  \
      sx -= tl;                                                                \
    }                                                                          \
    LDS_BAR();                                                                 \
    if ((K) < 3) {                                                             \
      store_blk(ts, sPrev, tid, TPF);                                          \
      load_x(xb, R0 + 16, tid, XGN);                                           \
    }                                                                          \
    if ((K) < 2) load_blk(tb, bbk + 3, tid, TPFN);                             \
    {                                                                          \
      const int cb = 36 * (sub >> 1) + 16 * (sub & 1);                         \
      const float* vb = &vls[s2row * VST + cb];                                \
      float q16[16];                                                           \
      float run = 0.f;                                                         \
      _Pragma("unroll")                                                        \
      for (int e = 0; e < 4; ++e) {                                            \
        float4 vv = *(const float4*)(vb + 4 * e);                              \
        q16[4 * e + 0] = run + vv.x;                                           \
        q16[4 * e + 1] = q16[4 * e + 0] + vv.y;                                \
        q16[4 * e + 2] = q16[4 * e + 1] + vv.z;                                \
        q16[4 * e + 3] = q16[4 * e + 2] + vv.w;                                \
        run = q16[4 * e + 3];                                                  \
      }                                                                        \
      float tot = q16[15], ss = tot;                                           \
      _Pragma("unroll")                                                        \
      for (int d = 1; d < 16; d <<= 1) {                                       \
        float uu = __shfl_up(ss, d, 64);                                       \
        if (sub >= d) ss += uu;                                                \
      }                                                                        \
      /* width-16 groups? No: sub is 0..31 within a row-pair wave; width-32 */ \
      {                                                                        \
        float uu = __shfl_up(ss, 16, 64);                                      \
        if (sub >= 16) ss += uu;                                               \
      }                                                                        \
      float pb = ss - tot;                                                     \
      _Pragma("unroll")                                                        \
      for (int j = 0; j < 16; ++j) q16[j] += pb;                               \
      float4 tq[4];                                                            \
      const float* tb2 = &ts[sCur * SLOT + s2row * TSR + cb];                  \
      _Pragma("unroll")                                                        \
      for (int e = 0; e < 4; ++e) tq[e] = *(const float4*)(tb2 + 4 * e);       \
      _Pragma("unroll")                                                        \
      for (int e = 0; e < 4; ++e) {                                            \
        float xa[4] = {XG[e].x, XG[e].y, XG[e].z, XG[e].w};                    \
        float ta[4] = {tq[e].x, tq[e].y, tq[e].z, tq[e].w};                    \
        _Pragma("unroll")                                                      \
        for (int l = 0; l < 4; ++l) {                                          \
          const int j = 4 * e + l;                                             \
          float hi;                                                            \
          if (j == 0) {                                                        \
            hi = q16[15];                                                      \
          } else {                                                             \
            float gd = __shfl_down(q16[j - 1], 1, 64);                         \
            hi = (sub == 31) ? q16[15] : gd;                                   \
          }                                                                    \
          float gu = __shfl_up(q16[j], 1, 64);                                 \
          float lo = (sub == 0) ? 0.f : gu;                                    \
          float box = hi - lo;                                                 \
          float tv = ta[l], xv = xa[l];                                        \
          float w  = fmaf(5.0f, fabsf(box * inv_area - tv), 1.0f);             \
          float ez = __expf(-fabsf(xv));                                       \
          float iv = 1.0f / (1.0f + ez);                                       \
          float p  = (xv >= 0.f) ? iv : ez * iv;                               \
          float bce = fmaxf(xv, 0.f) - xv * tv + __logf(1.0f + ez);            \
          aW += w;                                                             \
          aWB = fmaf(w, bce, aWB);                                             \
          aI  = fmaf(p * tv, w, aI);                                           \
          aU  = fmaf(p + tv, w, aU);                                           \
        }                                                                      \
      }                                                                        \
    }                                                                          \
    LDS_BAR();                                                                 \
  }

__global__ __launch_bounds__(NTH, 2) void sloss_main(const float* __restrict__ x,
                                                     const float* __restrict__ t,
                                                     float* __restrict__ part) {
  __shared__ __align__(16) float ts[3 * SLOT];    // 111,360 B rolling t window
  __shared__ __align__(16) float vls[16 * VST];   //  37,376 B vertical sums
  __shared__ float red[8][4];

  const int tid  = threadIdx.x;
  // band-to-XCD swizzle: all 8 bands of an image stay on one XCD's L2 so the
  // 15-row band-boundary halos get cross-block L2 hits.
  const int xcd  = blockIdx.x & 7;
  const int kb   = blockIdx.x >> 3;        // 0..31
  const int img  = (xcd << 2) | (kb >> 3); // 4 images per XCD
  const int band = kb & 7;
  const int bb0  = band * 4;               // first 16-row block of this band
  const float* tb = t + (size_t)img * (IMG_H * IMG_W);
  const float* xb = x + (size_t)img * (IMG_H * IMG_W);

  const int li    = tid + 4 * (tid >> 5);  // vidx(col) for this thread's column
  const int s2row = tid >> 5;              // stage-2 row 0..15
  const int sub   = tid & 31;              // stage-2 16-col chunk 0..31
  const float inv_area = 1.0f / 961.0f;

  // ---- prologue: stage blocks bb0-1, bb0, bb0+1 into the rolling window ----
  {
    float4 g0[4], g1[4], g2[4];
    load_blk(tb, bb0 - 1, tid, g0);
    load_blk(tb, bb0,     tid, g1);
    load_blk(tb, bb0 + 1, tid, g2);
    store_blk(ts, (bb0 + 2) % 3, tid, g0);
    store_blk(ts, (bb0 + 3) % 3, tid, g1);
    store_blk(ts, (bb0 + 4) % 3, tid, g2);
  }
  LDS_BAR();

  // issue iter-0 x tile + block bb0+2 prefetch; they fly during warm-up+march
  float4 xgA[4], xgB[4], tpA[4], tpB[4];
  load_x(xb, bb0 * 16, tid, xgA);
  load_blk(tb, bb0 + 2, tid, tpA);

  // ---- warm-up: sx = sum of t rows [band*64-15, band*64+14] for col tid ----
  float sx = 0.f;
#pragma unroll
  for (int j = -15; j < 15; ++j) {
    int a = bb0 * 16 + j;                  // may be negative: >>4 floors, &15 mods
    int b = a >> 4;
    sx += ts[((b + 3) % 3) * SLOT + (a & 15) * TSR + li];
  }

  float aW = 0.f, aWB = 0.f, aI = 0.f, aU = 0.f;

  ITER(0, xgA, tpA, xgB, tpB)
  ITER(1, xgB, tpB, xgA, tpA)
  ITER(2, xgA, tpA, xgB, tpB)
  ITER(3, xgB, tpB, xgA, tpA)

  aW  = wave_reduce(aW);
  aWB = wave_reduce(aWB);
  aI  = wave_reduce(aI);
  aU  = wave_reduce(aU);
  const int wv = tid >> 6, ln = tid & 63;
  if (ln == 0) { red[wv][0] = aW; red[wv][1] = aWB; red[wv][2] = aI; red[wv][3] = aU; }
  __syncthreads();
  if (tid < 4) {
    float v = 0.f;
#pragma unroll
    for (int w8 = 0; w8 < 8; ++w8) v += red[w8][tid];
    part[(img * BANDS + band) * 4 + tid] = v;
  }
}

// ---- finalize: reduce 256 block-partials -> scalar loss ----
__global__ void sloss_final(const float* __restrict__ part,
                            float* __restrict__ out) {
  __shared__ float s[128];
  int tid = threadIdx.x;          // 128 threads
  int img = tid >> 2, q = tid & 3;
  float v = 0.f;
#pragma unroll
  for (int g = 0; g < BANDS; ++g) v += part[((img << 3) + g) * 4 + q];
  s[tid] = v;
  __syncthreads();
  float loss = 0.f;
  if (tid < NB) {
    float aW  = s[tid * 4 + 0];
    float aWB = s[tid * 4 + 1];
    float aI  = s[tid * 4 + 2];
    float aU  = s[tid * 4 + 3];
    loss = aWB / aW + 1.0f - (aI + 1.0f) / (aU - aI + 1.0f);
  }
  loss = wave_reduce(loss);
  if (tid == 0) out[0] = loss * (1.0f / (float)NB);
}

extern "C" void kernel_launch(void* const* d_in, const int* in_sizes, int n_in,
                              void* d_out, int out_size, void* d_ws, size_t ws_size,
                              hipStream_t stream) {
  const float* x = (const float*)d_in[0];
  const float* t = (const float*)d_in[1];
  float* part = (float*)d_ws;     // 256 x 4 floats, fully overwritten

  sloss_main<<<NBLK, NTH, 0, stream>>>(x, t, part);
  sloss_final<<<1, 128, 0, stream>>>(part, (float*)d_out);
}

// Round 6
// 100.499 us; speedup vs baseline: 1.1370x; 1.0433x over previous
//
#include <hip/hip_runtime.h>
#include <math.h>

// StructureLoss — R13: traffic economy of R8 + phase interleave of R7.
// Ledger: barrier texture falsified twice (R9, R12 both <= noise); only real
// win ever = traffic cut (R7->R8, 118->83MB, -6us). R12 counters: HBM 7%,
// VALU 15%, occ 22% at 1 blk/CU -> bursty memory duty cycle with no second
// block to fill the march/scan gaps. R13 drops the 111KB raw-t LDS window
// (keeps only 37.4KB skewed vls): 512 blocks (32 img x 16 bands of 32 rows,
// XCD-swizzled) x 512 thr -> 2 independent blocks/CU, 16 waves. Phase 1 =
// thread-per-col register running sum straight from global; head rows are
// the only HBM-new reads, tail rows + stage-2 t re-reads hit L1/L2 (~60KB
// reuse distance), band halos share the XCD L2. Loads batched 16-ahead;
// stage-2 x/t issued one phase early. Arithmetic order (warm-up sequential,
// running add/sub, q16 prefix, width-32 scan, red order) identical to the
// absmax-0-proven R10/R12 paths.

#define IMG_H 512
#define IMG_W 512
#define NB    32
#define HW    (IMG_H * IMG_W)
#define BANDS 16              // 32-row bands per image
#define NBLK  (NB * BANDS)    // 512 blocks -> 2 per CU
#define NTH   512
#define VST   584             // vls row stride (floats), skewed layout

__device__ __forceinline__ float wave_reduce(float v) {
#pragma unroll
  for (int off = 32; off > 0; off >>= 1) v += __shfl_down(v, off, 64);
  return v;
}

// stage2 for 16 rows starting at vls row 0; consumes XGv/TGv register tiles
#define STAGE2(XGv, TGv)                                                       \
  {                                                                            \
    const float* vb = &vls[row * VST + cb];                                    \
    float q16[16];                                                             \
    {                                                                          \
      float run = 0.f;                                                         \
      _Pragma("unroll")                                                        \
      for (int e = 0; e < 4; ++e) {                                            \
        float4 vv = *(const float4*)(vb + 4 * e);                              \
        q16[4 * e + 0] = run + vv.x;                                           \
        q16[4 * e + 1] = q16[4 * e + 0] + vv.y;                                \
        q16[4 * e + 2] = q16[4 * e + 1] + vv.z;                                \
        q16[4 * e + 3] = q16[4 * e + 2] + vv.w;                                \
        run = q16[4 * e + 3];                                                  \
      }                                                                        \
    }                                                                          \
    {                                                                          \
      float tot = q16[15], ss = tot;                                           \
      _Pragma("unroll")                                                        \
      for (int d = 1; d < 32; d <<= 1) {                                       \
        float uu = __shfl_up(ss, d, 64);                                       \
        if (sub >= d) ss += uu;                                                \
      }                                                                        \
      float pb = ss - tot;                                                     \
      _Pragma("unroll")                                                        \
      for (int j = 0; j < 16; ++j) q16[j] += pb;   /* q16[j] = P[16*sub+j] */  \
    }                                                                          \
    _Pragma("unroll")                                                          \
    for (int e = 0; e < 4; ++e) {                                              \
      float xa[4] = {XGv[e].x, XGv[e].y, XGv[e].z, XGv[e].w};                  \
      float ta[4] = {TGv[e].x, TGv[e].y, TGv[e].z, TGv[e].w};                  \
      _Pragma("unroll")                                                        \
      for (int l = 0; l < 4; ++l) {                                            \
        const int j = 4 * e + l;                                               \
        float hi;                                                              \
        if (j == 0) {                                                          \
          hi = q16[15];                                                        \
        } else {                                                               \
          float gd = __shfl_down(q16[j - 1], 1, 64);                           \
          hi = (sub == 31) ? q16[15] : gd;         /* P[min(c+15,511)] */      \
        }                                                                      \
        float gu = __shfl_up(q16[j], 1, 64);                                   \
        float lo = (sub == 0) ? 0.f : gu;          /* P[c-16] or 0 */          \
        float box = hi - lo;                                                   \
        float tv = ta[l], xv = xa[l];                                          \
        float w   = fmaf(5.0f, fabsf(box * inv_area - tv), 1.0f);              \
        float ez  = __expf(-fabsf(xv));                                        \
        float iv  = 1.0f / (1.0f + ez);                                        \
        float p   = (xv >= 0.f) ? iv : ez * iv;    /* sigmoid(x) */            \
        float bce = fmaxf(xv, 0.f) - xv * tv + __logf(1.0f + ez);              \
        aW  += w;                                                              \
        aWB = fmaf(w, bce, aWB);                                               \
        aI  = fmaf(p * tv, w, aI);                                             \
        aU  = fmaf(p + tv, w, aU);                                             \
      }                                                                        \
    }                                                                          \
  }

// 512 blocks: xcd(8) x k(64); 4 images per XCD, 16 bands per image.
__global__ __launch_bounds__(NTH, 4) void sloss_main(const float* __restrict__ x,
                                                     const float* __restrict__ t,
                                                     float* __restrict__ part) {
  __shared__ __align__(16) float vls[16 * VST];   // 37,376 B (only LDS tile)
  __shared__ float red[8][4];

  const int tid  = threadIdx.x;
  const int bid  = blockIdx.x;
  const int xcd  = bid & 7;
  const int k    = bid >> 3;               // 0..63
  const int img  = (xcd << 2) | (k >> 4);  // 4 images per XCD
  const int band = k & 15;                 // 16 bands per image
  const int r0   = band * 32;
  const float* tb = t + (size_t)img * HW;
  const float* xb = x + (size_t)img * HW;
  const float* tc = tb + tid;              // phase-1: thread = column tid

  const int li  = tid + 4 * (tid >> 5);    // skewed col index for vls writes
  const int row = tid >> 5;                // stage-2 row 0..15
  const int sub = tid & 31;                // stage-2 16-col chunk 0..31
  const int cb  = 36 * (sub >> 1) + 16 * (sub & 1);
  const float inv_area = 1.0f / 961.0f;

  // ---- warm-up: sum of t rows [r0-15, r0+14] for this column ----
  float sum = 0.f;
  {
    float w[30];
#pragma unroll
    for (int j = 0; j < 30; ++j) {
      int r = r0 - 15 + j;
      w[j] = ((unsigned)r < IMG_H) ? tc[(size_t)r * IMG_W] : 0.f;
    }
#pragma unroll
    for (int j = 0; j < 30; ++j) sum += w[j];
  }

  // ---- issue sub-iter-0 operands: head/tail rows + stage-2 x/t tiles ----
  float hd0[16], tl0[16];
#pragma unroll
  for (int i = 0; i < 16; ++i) {
    int r = r0 + i + 15;
    hd0[i] = ((unsigned)r < IMG_H) ? tc[(size_t)r * IMG_W] : 0.f;
  }
#pragma unroll
  for (int i = 0; i < 16; ++i) {
    int r = r0 + i - 15;
    tl0[i] = ((unsigned)r < IMG_H) ? tc[(size_t)r * IMG_W] : 0.f;
  }
  float4 xg0[4], tg0[4];
  const size_t base0 = (size_t)(r0 + row) * IMG_W + 16 * sub;
#pragma unroll
  for (int e = 0; e < 4; ++e) xg0[e] = *(const float4*)(xb + base0 + 4 * e);
#pragma unroll
  for (int e = 0; e < 4; ++e) tg0[e] = *(const float4*)(tb + base0 + 4 * e);

  float aW = 0.f, aWB = 0.f, aI = 0.f, aU = 0.f;

  // ---- sub-iter 0: march rows r0..r0+15 ----
#pragma unroll
  for (int i = 0; i < 16; ++i) {
    sum += hd0[i];
    vls[i * VST + li] = sum;
    sum -= tl0[i];
  }
  __syncthreads();

  // issue sub-iter-1 phase-1 operands; they fly under stage-2 s0
  float hd1[16], tl1[16];
#pragma unroll
  for (int i = 0; i < 16; ++i) {
    int r = r0 + 16 + i + 15;
    hd1[i] = ((unsigned)r < IMG_H) ? tc[(size_t)r * IMG_W] : 0.f;
  }
#pragma unroll
  for (int i = 0; i < 16; ++i) {
    int r = r0 + 16 + i - 15;
    tl1[i] = ((unsigned)r < IMG_H) ? tc[(size_t)r * IMG_W] : 0.f;
  }

  STAGE2(xg0, tg0)
  __syncthreads();

  // ---- sub-iter 1: march rows r0+16..r0+31; stage-2 tiles issued early ----
  float4 xg1[4], tg1[4];
  const size_t base1 = base0 + (size_t)16 * IMG_W;
#pragma unroll
  for (int e = 0; e < 4; ++e) xg1[e] = *(const float4*)(xb + base1 + 4 * e);
#pragma unroll
  for (int e = 0; e < 4; ++e) tg1[e] = *(const float4*)(tb + base1 + 4 * e);
#pragma unroll
  for (int i = 0; i < 16; ++i) {
    sum += hd1[i];
    vls[i * VST + li] = sum;
    sum -= tl1[i];
  }
  __syncthreads();

  STAGE2(xg1, tg1)

  // ---- block reduction ----
  aW  = wave_reduce(aW);
  aWB = wave_reduce(aWB);
  aI  = wave_reduce(aI);
  aU  = wave_reduce(aU);
  const int wv = tid >> 6, ln = tid & 63;
  if (ln == 0) { red[wv][0] = aW; red[wv][1] = aWB; red[wv][2] = aI; red[wv][3] = aU; }
  __syncthreads();
  if (tid < 4) {
    float v = 0.f;
#pragma unroll
    for (int w8 = 0; w8 < 8; ++w8) v += red[w8][tid];
    part[(img * BANDS + band) * 4 + tid] = v;
  }
}

// ---- finalize: reduce 512 block-partials -> scalar loss ----
__global__ void sloss_final(const float* __restrict__ part,
                            float* __restrict__ out) {
  __shared__ float s[128];
  int tid = threadIdx.x;          // 128 threads
  int img = tid >> 2, q = tid & 3;
  float v = 0.f;
#pragma unroll 4
  for (int g = 0; g < BANDS; ++g) v += part[((img << 4) + g) * 4 + q];
  s[tid] = v;
  __syncthreads();
  float loss = 0.f;
  if (tid < NB) {
    float aW  = s[tid * 4 + 0];
    float aWB = s[tid * 4 + 1];
    float aI  = s[tid * 4 + 2];
    float aU  = s[tid * 4 + 3];
    loss = aWB / aW + 1.0f - (aI + 1.0f) / (aU - aI + 1.0f);
  }
  loss = wave_reduce(loss);
  if (tid == 0) out[0] = loss * (1.0f / (float)NB);
}

extern "C" void kernel_launch(void* const* d_in, const int* in_sizes, int n_in,
                              void* d_out, int out_size, void* d_ws, size_t ws_size,
                              hipStream_t stream) {
  const float* x = (const float*)d_in[0];
  const float* t = (const float*)d_in[1];
  float* part = (float*)d_ws;     // 512 x 4 floats, fully overwritten

  sloss_main<<<NBLK, NTH, 0, stream>>>(x, t, part);
  sloss_final<<<1, 128, 0, stream>>>(part, (float*)d_out);
}